// Round 6
// baseline (454.903 us; speedup 1.0000x reference)
//
#include <hip/hip_runtime.h>
#include <math.h>

#define HIDN 2048
#define NHEADS 16
#define HDIM 128
#define SEQ 2048
#define NB 2

// scale * log2(e), folded into Wq/bq so S arrives pre-scaled for exp2.
#define C2 0.12751744154f

typedef __bf16 bf16x8 __attribute__((ext_vector_type(8)));
typedef float f32x4 __attribute__((ext_vector_type(4)));

__device__ __forceinline__ unsigned short f32_to_bf16(float f) {
  unsigned int u = __float_as_uint(f);
  u += 0x7FFFu + ((u >> 16) & 1u);   // round-to-nearest-even
  return (unsigned short)(u >> 16);
}

__device__ __forceinline__ unsigned pack_bf16x2(float a, float b) {
  return (unsigned)f32_to_bf16(a) | ((unsigned)f32_to_bf16(b) << 16);
}

// pack two f32 to bf16x2 by TRUNCATION in one v_perm_b32.
__device__ __forceinline__ unsigned pack_bf16x2_trunc(float a, float b) {
  return __builtin_amdgcn_perm(__float_as_uint(b), __float_as_uint(a), 0x07060302u);
}

// async global->LDS, 16B/lane. LDS dest is wave-uniform base + lane*16 (m104/m108).
__device__ __forceinline__ void gload_lds16(const void* g, void* l) {
  __builtin_amdgcn_global_load_lds(
      (__attribute__((address_space(1))) void*)(g),
      (__attribute__((address_space(3))) void*)(l), 16, 0, 0);
}

// ---- in-device grid barrier (plain launch, graph-capturable) ----
// Counters zeroed by hipMemsetAsync pre-launch. 512 blocks co-resident by
// construction (64 KiB LDS -> 2/CU, launch_bounds(256,2) -> 8 waves/CU), so the
// spin cannot starve. atomicAdd = device scope (m20); __threadfence = agent-scope
// release/acquire (G16 cross-XCD mitigation).
__device__ __forceinline__ void gbar(unsigned* cnt, unsigned nb) {
  __syncthreads();
  if (threadIdx.x == 0) {
    __threadfence();                       // release: publish this block's stores
    atomicAdd(cnt, 1u);
    while (atomicAdd(cnt, 0u) < nb) __builtin_amdgcn_s_sleep(2);
    __threadfence();                       // acquire: invalidate stale caches
  }
  __syncthreads();
}

// ---------------- phase A body: cast + Wq/Wo transpose + Wk/Wv transpose + bias -------
// blk < 8192: f32->bf16 cast of hidden; [8192,16384): wtrans_big (Wq*C2 / Wo);
// [16384,16896): wtrans_small (Wk(+bias) / Wv). Caller syncs between iterations.
__device__ __forceinline__ void prep_blk(
    int blk, char* smemraw,
    const float* hidden, unsigned short* hb,
    const float* wq, unsigned short* dq,
    const float* wo, unsigned short* do_,
    const float* wk, const float* wv,
    unsigned short* dk, unsigned short* dv,
    const float* bq, const float* bk, const float* bv, float* biasout) {
  float (*tile)[33] = (float(*)[33])smemraw;
  const int tx = threadIdx.x & 31, ty = threadIdx.x >> 5;
  if (blk < 8192) {
    int i = blk * 256 + threadIdx.x;
    float4 v = ((const float4*)hidden)[i];
    ushort4 o;
    o.x = f32_to_bf16(v.x); o.y = f32_to_bf16(v.y);
    o.z = f32_to_bf16(v.z); o.w = f32_to_bf16(v.w);
    ((ushort4*)hb)[i] = o;
    return;
  }
  if (blk < 16384) {
    int r = blk - 8192;
    const int z = r >> 12; r &= 4095;
    const int bx = r & 63, by = r >> 6;
    const float* src = z ? wo : wq;
    unsigned short* dst = z ? do_ : dq;
    const float m = z ? 1.0f : C2;
    const int c0 = bx * 32, r0 = by * 32;
#pragma unroll
    for (int i = 0; i < 32; i += 8)
      tile[ty + i][tx] = src[(size_t)(r0 + ty + i) * 2048 + c0 + tx];
    __syncthreads();
#pragma unroll
    for (int i = 0; i < 32; i += 8)
      dst[(size_t)(c0 + ty + i) * 2048 + r0 + tx] = f32_to_bf16(tile[tx][ty + i] * m);
    return;
  }
  {
    int r = blk - 16384;
    const int z = r >> 8; r &= 255;
    const int bx = r & 3, by = r >> 2;
    const float* src = z ? wv : wk;
    unsigned short* dst = z ? dv : dk;
    const int c0 = bx * 32, r0 = by * 32;
#pragma unroll
    for (int i = 0; i < 32; i += 8)
      tile[ty + i][tx] = src[(size_t)(r0 + ty + i) * 128 + c0 + tx];
    __syncthreads();
#pragma unroll
    for (int i = 0; i < 32; i += 8)
      dst[(size_t)(c0 + ty + i) * 2048 + r0 + tx] = f32_to_bf16(tile[tx][ty + i]);
    if (z == 0) {
      int lb = by * 4 + bx;
      if (lb < 9) {
        int i = lb * 256 + threadIdx.x;
        if (i < 2304)
          biasout[i] = (i < 2048) ? bq[i] * C2
                                  : ((i < 2176) ? bk[i - 2048] : bv[i - 2176]);
      }
    }
  }
}

// ---------------- gemm_bt body: C[M][N] = A[M][K] * BT[N][K]^T + bias (R0-proven) -----
// WRITE_VT=1 (QKV gemm): epilogue ALSO writes the key-permuted V transpose directly
// from registers for cols >= 2176 (perm only touches bits >= 2, so 4 consecutive
// rows per fragment stay contiguous -> one 8B store).
template <int BN, int WRITE_VT>
__device__ __forceinline__ void gemm_bt_blk(
    int bxi, int byi, char* smemraw,
    const unsigned short* A, const unsigned short* BT,
    const float* bias, void* C, unsigned short* vtout,
    int K, int ldc, int outBf16) {
  constexpr int NT = BN / 32;
  unsigned short* As = (unsigned short*)smemraw;        // 128*64*2 = 16 KiB
  unsigned short* Bs = As + 128 * 64;                   // BN*64*2
  const int tid = threadIdx.x;
  const int lane = tid & 63;
  const int wave = tid >> 6;
  const int wr = wave >> 1, wc = wave & 1;
  const int ml = lane & 15, quad = lane >> 4;
  const long bm = (long)bxi * 128;
  const long bn = (long)byi * BN;

  const f32x4 zero4 = {0.f, 0.f, 0.f, 0.f};
  f32x4 acc[4][NT];
#pragma unroll
  for (int mt = 0; mt < 4; ++mt)
#pragma unroll
    for (int nt = 0; nt < NT; ++nt) acc[mt][nt] = zero4;

  const int srow = lane >> 3;
  const int scol = ((lane & 7) ^ srow) * 8;

  for (int k0 = 0; k0 < K; k0 += 64) {
    __syncthreads();
#pragma unroll
    for (int r = 0; r < 4; ++r) {
      const int rowb = r * 32 + wave * 8;
      gload_lds16(A + (bm + rowb + srow) * (long)K + k0 + scol, &As[rowb * 64]);
    }
#pragma unroll
    for (int r = 0; r < NT; ++r) {
      const int rowb = r * 32 + wave * 8;
      gload_lds16(BT + (bn + rowb + srow) * (long)K + k0 + scol, &Bs[rowb * 64]);
    }
    __syncthreads();
#pragma unroll
    for (int kk = 0; kk < 64; kk += 32) {
      const int g0 = (kk >> 3) + quad;
      bf16x8 af[4], bf[NT];
#pragma unroll
      for (int mt = 0; mt < 4; ++mt)
        af[mt] = *(const bf16x8*)&As[(wr * 64 + mt * 16 + ml) * 64 +
                                     ((g0 ^ (ml & 7)) << 3)];
#pragma unroll
      for (int nt = 0; nt < NT; ++nt)
        bf[nt] = *(const bf16x8*)&Bs[(wc * (BN / 2) + nt * 16 + ml) * 64 +
                                     ((g0 ^ (ml & 7)) << 3)];
#pragma unroll
      for (int mt = 0; mt < 4; ++mt)
#pragma unroll
        for (int nt = 0; nt < NT; ++nt)
          acc[mt][nt] = __builtin_amdgcn_mfma_f32_16x16x32_bf16(
              af[mt], bf[nt], acc[mt][nt], 0, 0, 0);
    }
  }

#pragma unroll
  for (int mt = 0; mt < 4; ++mt) {
#pragma unroll
    for (int nt = 0; nt < NT; ++nt) {
      const long col = bn + wc * (BN / 2) + nt * 16 + ml;
      const float bval = bias ? bias[col] : 0.f;
      float vv[4];
#pragma unroll
      for (int r = 0; r < 4; ++r) {
        const long row = bm + wr * 64 + mt * 16 + quad * 4 + r;
        const float v = acc[mt][nt][r] + bval;
        vv[r] = v;
        if (outBf16)
          ((unsigned short*)C)[row * ldc + col] = f32_to_bf16(v);
        else
          ((float*)C)[row * ldc + col] = v;
      }
      if (WRITE_VT) {
        if (col >= 2176) {
          const long row0 = bm + wr * 64 + mt * 16 + quad * 4;
          const int b = (int)(row0 >> 11);
          const int s0 = (int)(row0 & 2047);
          const int P = (s0 & ~63) | (((s0 >> 5) & 1) * 32 +
                                      (((s0 >> 2) & 3) * 8) +
                                      (((s0 >> 4) & 1) * 4));
          uint2 w;
          w.x = pack_bf16x2(vv[0], vv[1]);
          w.y = pack_bf16x2(vv[2], vv[3]);
          *(uint2*)&vtout[((long)b * 128 + (col - 2176)) * SEQ + P] = w;
        }
      }
    }
  }
}

// ---------------- flash MQA attention body (R4 counted-vmcnt version, passed) ---------
// 32 qrows/wave. S^T = K·Q^T (K from LDS dbuf as A, pre-scaled Q registers as B).
// P = exp2(S) in registers (v_perm truncation pack), feeds PV directly as B-operand
// (V columns key-permuted at vt-write). Split counted waits: vmcnt(4) forces K-half,
// vmcnt(8) forces V-half (next tile's 8 loads stay flying). Row-sums via ones MFMA.
__device__ __forceinline__ void attn_blk(
    int qblk, int h, int b, char* smemraw,
    const unsigned short* __restrict__ qkv,
    const unsigned short* __restrict__ vt,
    unsigned short* __restrict__ outp) {
  unsigned short (*Ks)[64 * 128] = (unsigned short(*)[64 * 128])smemraw;          // 32 KiB
  unsigned short (*VTs)[128 * 64] = (unsigned short(*)[128 * 64])(smemraw + 32768); // 32 KiB

  const int lane = threadIdx.x & 63;
  const int wave = threadIdx.x >> 6;
  const int ml = lane & 15, quad = lane >> 4;
  const long q0 = (long)qblk * 128;
  const long base = (long)b * SEQ;

  // Q fragments (B-operand of S^T); Wq pre-scaled by C2.
  bf16x8 aq[2][4];
#pragma unroll
  for (int n = 0; n < 2; ++n) {
    const unsigned short* qrow =
        qkv + (base + q0 + wave * 32 + n * 16 + ml) * 2304 + h * 128;
#pragma unroll
    for (int ks = 0; ks < 4; ++ks)
      aq[n][ks] = *(const bf16x8*)(qrow + ks * 32 + quad * 8);
  }

  const f32x4 zero4 = {0.f, 0.f, 0.f, 0.f};
  f32x4 o[8][2];
#pragma unroll
  for (int mt2 = 0; mt2 < 8; ++mt2)
#pragma unroll
    for (int n = 0; n < 2; ++n) o[mt2][n] = zero4;
  f32x4 o9[2] = {zero4, zero4};  // ones-row accumulator: row0 = sum_k P = l

  // ones-tile A-frag: row 0 (lane ml==0) = 1.0bf16, other rows 0.
  bf16x8 ones_af;
  {
    union { unsigned u[4]; bf16x8 v; } cv;
    const unsigned w = (ml == 0) ? 0x3F803F80u : 0u;
    cv.u[0] = w; cv.u[1] = w; cv.u[2] = w; cv.u[3] = w;
    ones_af = cv.v;
  }

  // staging lane decomposition
  const int srowK = lane >> 4;
  const int scolK = ((lane & 15) ^ (wave * 4 + srowK)) * 8;
  const int srowV = lane >> 3;
  const int scolV = ((lane & 7) ^ srowV) * 8;
  const unsigned short* kp = qkv + (base + srowK) * 2304 + 2048 + scolK;
  const unsigned short* vp = vt + ((long)b * 128 + srowV) * SEQ + scolV;

  // K loads FIRST, V loads SECOND (vmcnt oldest-first retirement separates halves).
  auto stage = [&](int buf, int ktn) {
    const unsigned short* kpp = kp + (long)ktn * (64 * 2304);
    const unsigned short* vpp = vp + ktn * 64;
#pragma unroll
    for (int r = 0; r < 4; ++r) {
      const int rowb = r * 16 + wave * 4;
      gload_lds16(kpp + (long)rowb * 2304, &Ks[buf][rowb * 128]);
    }
#pragma unroll
    for (int r = 0; r < 4; ++r) {
      const int rowb = r * 32 + wave * 8;
      gload_lds16(vpp + (long)rowb * SEQ, &VTs[buf][rowb * 64]);
    }
  };

  stage(0, 0);

  for (int kt = 0; kt < SEQ / 64; ++kt) {
    const int cur = kt & 1;
    // force this tile's K-half only (own wave), then make all waves' K visible.
    asm volatile("s_waitcnt vmcnt(4)" ::: "memory");
    __builtin_amdgcn_s_barrier();
    if (kt < SEQ / 64 - 1) stage(cur ^ 1, kt + 1);  // prefetch overlaps compute

    // S^T = K·Q^T : 4 key-mtiles x 2 qrow-ntiles x 4 ksteps (d); pre-scaled.
    f32x4 s[4][2];
#pragma unroll
    for (int mt = 0; mt < 4; ++mt)
#pragma unroll
      for (int n = 0; n < 2; ++n) s[mt][n] = zero4;
#pragma unroll
    for (int ks = 0; ks < 4; ++ks) {
#pragma unroll
      for (int mt = 0; mt < 4; ++mt) {
        bf16x8 ak = *(const bf16x8*)&Ks[cur][(mt * 16 + ml) * 128 +
                                            (((ks * 4 + quad) ^ ml) << 3)];
#pragma unroll
        for (int n = 0; n < 2; ++n)
          s[mt][n] = __builtin_amdgcn_mfma_f32_16x16x32_bf16(
              ak, aq[n][ks], s[mt][n], 0, 0, 0);
      }
    }

    // P = exp2(S) in registers; truncation-pack to bf16 pairs (1 v_perm each).
    unsigned pk[2][4][2];
#pragma unroll
    for (int mt = 0; mt < 4; ++mt)
#pragma unroll
      for (int n = 0; n < 2; ++n) {
        const float p0 = __builtin_amdgcn_exp2f(s[mt][n][0]);
        const float p1 = __builtin_amdgcn_exp2f(s[mt][n][1]);
        const float p2 = __builtin_amdgcn_exp2f(s[mt][n][2]);
        const float p3 = __builtin_amdgcn_exp2f(s[mt][n][3]);
        pk[n][mt][0] = pack_bf16x2_trunc(p0, p1);
        pk[n][mt][1] = pack_bf16x2_trunc(p2, p3);
      }

    // force this tile's V-half (leaves next tile's 8 loads in flight), sync, PV.
    if (kt < SEQ / 64 - 1)
      asm volatile("s_waitcnt vmcnt(8)" ::: "memory");
    else
      asm volatile("s_waitcnt vmcnt(0)" ::: "memory");
    __builtin_amdgcn_s_barrier();

    // O^T += V^T·P^T, plus ones-row MFMA accumulating l from the SAME bf16 P.
#pragma unroll
    for (int ks2 = 0; ks2 < 2; ++ks2) {
      bf16x8 bp[2];
#pragma unroll
      for (int n = 0; n < 2; ++n) {
        union { unsigned u[4]; bf16x8 v; } cv;
        cv.u[0] = pk[n][2 * ks2][0];
        cv.u[1] = pk[n][2 * ks2][1];
        cv.u[2] = pk[n][2 * ks2 + 1][0];
        cv.u[3] = pk[n][2 * ks2 + 1][1];
        bp[n] = cv.v;
      }
#pragma unroll
      for (int n = 0; n < 2; ++n)
        o9[n] = __builtin_amdgcn_mfma_f32_16x16x32_bf16(
            ones_af, bp[n], o9[n], 0, 0, 0);
#pragma unroll
      for (int mt2 = 0; mt2 < 8; ++mt2) {
        bf16x8 av = *(const bf16x8*)&VTs[cur][(mt2 * 16 + ml) * 64 +
                                             (((ks2 * 4 + quad) ^ (ml & 7)) << 3)];
#pragma unroll
        for (int n = 0; n < 2; ++n)
          o[mt2][n] = __builtin_amdgcn_mfma_f32_16x16x32_bf16(
              av, bp[n], o[mt2][n], 0, 0, 0);
      }
    }
  }

  // l lives at lane (quad=0, ml) reg0 of o9: broadcast across the 16-group.
  float inv[2];
#pragma unroll
  for (int n = 0; n < 2; ++n)
    inv[n] = 1.f / __shfl(o9[n][0], ml);

  // O^T C-layout: lane holds O[qrow=ml][d = mt2*16+quad*4+r] -> 8B packed stores.
#pragma unroll
  for (int n = 0; n < 2; ++n) {
    const long row = base + q0 + wave * 32 + n * 16 + ml;
#pragma unroll
    for (int mt2 = 0; mt2 < 8; ++mt2) {
      uint2 w;
      w.x = pack_bf16x2(o[mt2][n][0] * inv[n], o[mt2][n][1] * inv[n]);
      w.y = pack_bf16x2(o[mt2][n][2] * inv[n], o[mt2][n][3] * inv[n]);
      *(uint2*)&outp[row * HIDN + h * HDIM + mt2 * 16 + quad * 4] = w;
    }
  }
}

// ---------------- fused mega-kernel: 512 blocks x 256 threads, 2/CU, spin barriers ----
// Phase A: prep (33 grid-stride iterations = 16896 virtual blocks)
// Phase B: QKV gemm_bt<96> (768 tiles; blocks <256 take a second tile)
// Phase C: MQA attention (512 tiles, 1:1)
// Phase D: out-proj gemm_bt<128> (512 tiles, 1:1)
// In-device gbar() between phases replaces 3 kernel-launch gaps (~10 us each).
// LDS: 64 KiB union (attn's footprint) -> 2 blocks/CU co-resident = exactly 512.
__global__ __launch_bounds__(256, 2) void fused_mqa(
    const float* __restrict__ hidden,
    const float* __restrict__ Wq, const float* __restrict__ bq,
    const float* __restrict__ Wk, const float* __restrict__ bk,
    const float* __restrict__ Wv, const float* __restrict__ bv,
    const float* __restrict__ Wo, const float* __restrict__ bo,
    float* __restrict__ out,
    unsigned short* __restrict__ hb, unsigned short* __restrict__ wqkvT,
    unsigned short* __restrict__ woT, unsigned short* __restrict__ qkv,
    unsigned short* __restrict__ vt, float* __restrict__ biasqkv,
    unsigned* __restrict__ bar) {
  __shared__ __align__(16) char smem[65536];
  const int bid = blockIdx.x;
  unsigned short* dk = wqkvT + (size_t)2048 * 2048;
  unsigned short* dv = wqkvT + (size_t)2176 * 2048;
  unsigned short* attn = hb;  // aliases hb (dead after QKV gemm reads it)

  // ---- phase A: prep ----
  for (int i = 0; i < 33; ++i) {
    prep_blk(bid + 512 * i, smem, hidden, hb, Wq, wqkvT, Wo, woT, Wk, Wv,
             dk, dv, bq, bk, bv, biasqkv);
    __syncthreads();  // WAR guard on smem tile between iterations
  }
  gbar(&bar[0], 512);

  // ---- phase B: QKV projection + fused key-permuted V transpose (768 tiles) ----
  gemm_bt_blk<96, 1>(bid & 31, bid >> 5, smem, hb, wqkvT, biasqkv, qkv, vt,
                     2048, 2304, 1);
  if (bid < 256) {
    __syncthreads();
    const int vb = 512 + bid;
    gemm_bt_blk<96, 1>(vb & 31, vb >> 5, smem, hb, wqkvT, biasqkv, qkv, vt,
                       2048, 2304, 1);
  }
  gbar(&bar[32], 512);

  // ---- phase C: attention ----
  attn_blk(bid & 15, (bid >> 4) & 15, bid >> 8, smem, qkv, vt, attn);
  gbar(&bar[64], 512);

  // ---- phase D: output projection ----
  gemm_bt_blk<128, 0>(bid & 31, bid >> 5, smem, attn, woT, bo, out, nullptr,
                      2048, 2048, 0);
}

extern "C" void kernel_launch(void* const* d_in, const int* in_sizes, int n_in,
                              void* d_out, int out_size, void* d_ws, size_t ws_size,
                              hipStream_t stream) {
  const float* hidden = (const float*)d_in[0];
  const float* Wq = (const float*)d_in[1];
  const float* bq = (const float*)d_in[2];
  const float* Wk = (const float*)d_in[3];
  const float* bk = (const float*)d_in[4];
  const float* Wv = (const float*)d_in[5];
  const float* bv = (const float*)d_in[6];
  const float* Wo = (const float*)d_in[7];
  const float* bo = (const float*)d_in[8];
  float* out = (float*)d_out;

  char* ws = (char*)d_ws;
  const size_t MB = 1u << 20;
  unsigned short* hb    = (unsigned short*)(ws);            // 16 MiB [4096][2048] bf16 hidden / attn
  unsigned short* wqkvT = (unsigned short*)(ws + 16 * MB);  // 9 MiB  [2304][2048]
  unsigned short* woT   = (unsigned short*)(ws + 25 * MB);  // 8 MiB  [2048][2048]
  unsigned short* qkv   = (unsigned short*)(ws + 33 * MB);  // 18 MiB [4096][2304]
  unsigned short* vt    = (unsigned short*)(ws + 51 * MB);  // 1 MiB  [2][128][2048]
  float* biasqkv        = (float*)(ws + 52 * MB);           // 9 KiB  [2304]
  unsigned* bar         = (unsigned*)(ws + 53 * MB);        // 3 counters, 128B apart

  // reset barrier counters (hipMemsetAsync is graph-capture-safe; harness uses it)
  hipMemsetAsync(bar, 0, 384, stream);

  fused_mqa<<<512, 256, 0, stream>>>(hidden, Wq, bq, Wk, bk, Wv, bv, Wo, bo,
                                     out, hb, wqkvT, woT, qkv, vt, biasqkv, bar);
}

// Round 7
// 276.151 us; speedup vs baseline: 1.6473x; 1.6473x over previous
//
#include <hip/hip_runtime.h>
#include <math.h>

#define HIDN 2048
#define NHEADS 16
#define HDIM 128
#define SEQ 2048
#define NB 2

// scale * log2(e), folded into Wq/bq so S arrives pre-scaled for exp2.
#define C2 0.12751744154f

typedef __bf16 bf16x8 __attribute__((ext_vector_type(8)));
typedef float f32x4 __attribute__((ext_vector_type(4)));

__device__ __forceinline__ unsigned short f32_to_bf16(float f) {
  unsigned int u = __float_as_uint(f);
  u += 0x7FFFu + ((u >> 16) & 1u);   // round-to-nearest-even
  return (unsigned short)(u >> 16);
}

__device__ __forceinline__ unsigned pack_bf16x2(float a, float b) {
  return (unsigned)f32_to_bf16(a) | ((unsigned)f32_to_bf16(b) << 16);
}

// pack two f32 to bf16x2 by TRUNCATION in one v_perm_b32.
__device__ __forceinline__ unsigned pack_bf16x2_trunc(float a, float b) {
  return __builtin_amdgcn_perm(__float_as_uint(b), __float_as_uint(a), 0x07060302u);
}

// async global->LDS, 16B/lane. LDS dest is wave-uniform base + lane*16 (m104/m108).
__device__ __forceinline__ void gload_lds16(const void* g, void* l) {
  __builtin_amdgcn_global_load_lds(
      (__attribute__((address_space(1))) void*)(g),
      (__attribute__((address_space(3))) void*)(l), 16, 0, 0);
}

// ---------------- fused prep: cast + Wq/Wo transpose + Wk/Wv transpose + bias ---------
// blocks [0,8192): f32->bf16 cast of hidden (exactly covers 4096*2048/4 float4s)
// blocks [8192,16384): wtrans_big (z: 0=Wq*C2, 1=Wo), 64x64 tiles
// blocks [16384,16896): wtrans_small (z: 0=Wk(+bias), 1=Wv), 4x64 tiles
__global__ __launch_bounds__(256) void prep(
    const float* __restrict__ hidden, unsigned short* __restrict__ hb,
    const float* __restrict__ wq, unsigned short* __restrict__ dq,
    const float* __restrict__ wo, unsigned short* __restrict__ do_,
    const float* __restrict__ wk, const float* __restrict__ wv,
    unsigned short* __restrict__ dk, unsigned short* __restrict__ dv,
    const float* __restrict__ bq, const float* __restrict__ bk,
    const float* __restrict__ bv, float* __restrict__ biasout) {
  __shared__ float tile[32][33];
  const int blk = blockIdx.x;
  const int tx = threadIdx.x & 31, ty = threadIdx.x >> 5;
  if (blk < 8192) {
    int i = blk * 256 + threadIdx.x;
    float4 v = ((const float4*)hidden)[i];
    ushort4 o;
    o.x = f32_to_bf16(v.x); o.y = f32_to_bf16(v.y);
    o.z = f32_to_bf16(v.z); o.w = f32_to_bf16(v.w);
    ((ushort4*)hb)[i] = o;
    return;
  }
  if (blk < 16384) {
    int r = blk - 8192;
    const int z = r >> 12; r &= 4095;
    const int bx = r & 63, by = r >> 6;
    const float* src = z ? wo : wq;
    unsigned short* dst = z ? do_ : dq;
    const float m = z ? 1.0f : C2;
    const int c0 = bx * 32, r0 = by * 32;
#pragma unroll
    for (int i = 0; i < 32; i += 8)
      tile[ty + i][tx] = src[(size_t)(r0 + ty + i) * 2048 + c0 + tx];
    __syncthreads();
#pragma unroll
    for (int i = 0; i < 32; i += 8)
      dst[(size_t)(c0 + ty + i) * 2048 + r0 + tx] = f32_to_bf16(tile[tx][ty + i] * m);
    return;
  }
  {
    int r = blk - 16384;
    const int z = r >> 8; r &= 255;
    const int bx = r & 3, by = r >> 2;
    const float* src = z ? wv : wk;
    unsigned short* dst = z ? dv : dk;
    const int c0 = bx * 32, r0 = by * 32;
#pragma unroll
    for (int i = 0; i < 32; i += 8)
      tile[ty + i][tx] = src[(size_t)(r0 + ty + i) * 128 + c0 + tx];
    __syncthreads();
#pragma unroll
    for (int i = 0; i < 32; i += 8)
      dst[(size_t)(c0 + ty + i) * 2048 + r0 + tx] = f32_to_bf16(tile[tx][ty + i]);
    if (z == 0) {
      int lb = by * 4 + bx;
      if (lb < 9) {
        int i = lb * 256 + threadIdx.x;
        if (i < 2304)
          biasout[i] = (i < 2048) ? bq[i] * C2
                                  : ((i < 2176) ? bk[i - 2048] : bv[i - 2176]);
      }
    }
  }
}

// ---------------- gemm_bt: C[M][N] = A[M][K] * BT[N][K]^T + bias (R0-proven) ----------
// Single-buffered; relies on 3 blocks/CU co-residency for overlap (m114). Used for
// QKV (768 blocks = 3/CU). WRITE_VT=1: epilogue also writes key-permuted V transpose
// directly from registers for cols >= 2176 (perm only touches bits >= 2, so the 4
// consecutive rows per fragment stay contiguous -> one 8B store). R4-proven.
template <int BN, int WRITE_VT>
__global__ __launch_bounds__(256) void gemm_bt(
    const unsigned short* __restrict__ A,
    const unsigned short* __restrict__ BT,
    const float* __restrict__ bias,
    void* __restrict__ C, unsigned short* __restrict__ vtout,
    int K, int ldc, int outBf16) {
  constexpr int NT = BN / 32;
  __shared__ unsigned short As[128 * 64];
  __shared__ unsigned short Bs[BN * 64];
  const int tid = threadIdx.x;
  const int lane = tid & 63;
  const int wave = tid >> 6;
  const int wr = wave >> 1, wc = wave & 1;
  const int ml = lane & 15, quad = lane >> 4;
  const long bm = (long)blockIdx.x * 128;
  const long bn = (long)blockIdx.y * BN;

  const f32x4 zero4 = {0.f, 0.f, 0.f, 0.f};
  f32x4 acc[4][NT];
#pragma unroll
  for (int mt = 0; mt < 4; ++mt)
#pragma unroll
    for (int nt = 0; nt < NT; ++nt) acc[mt][nt] = zero4;

  const int srow = lane >> 3;
  const int scol = ((lane & 7) ^ srow) * 8;

  for (int k0 = 0; k0 < K; k0 += 64) {
    __syncthreads();
#pragma unroll
    for (int r = 0; r < 4; ++r) {
      const int rowb = r * 32 + wave * 8;
      gload_lds16(A + (bm + rowb + srow) * (long)K + k0 + scol, &As[rowb * 64]);
    }
#pragma unroll
    for (int r = 0; r < NT; ++r) {
      const int rowb = r * 32 + wave * 8;
      gload_lds16(BT + (bn + rowb + srow) * (long)K + k0 + scol, &Bs[rowb * 64]);
    }
    __syncthreads();
#pragma unroll
    for (int kk = 0; kk < 64; kk += 32) {
      const int g0 = (kk >> 3) + quad;
      bf16x8 af[4], bf[NT];
#pragma unroll
      for (int mt = 0; mt < 4; ++mt)
        af[mt] = *(const bf16x8*)&As[(wr * 64 + mt * 16 + ml) * 64 +
                                     ((g0 ^ (ml & 7)) << 3)];
#pragma unroll
      for (int nt = 0; nt < NT; ++nt)
        bf[nt] = *(const bf16x8*)&Bs[(wc * (BN / 2) + nt * 16 + ml) * 64 +
                                     ((g0 ^ (ml & 7)) << 3)];
#pragma unroll
      for (int mt = 0; mt < 4; ++mt)
#pragma unroll
        for (int nt = 0; nt < NT; ++nt)
          acc[mt][nt] = __builtin_amdgcn_mfma_f32_16x16x32_bf16(
              af[mt], bf[nt], acc[mt][nt], 0, 0, 0);
    }
  }

#pragma unroll
  for (int mt = 0; mt < 4; ++mt) {
#pragma unroll
    for (int nt = 0; nt < NT; ++nt) {
      const long col = bn + wc * (BN / 2) + nt * 16 + ml;
      const float bval = bias ? bias[col] : 0.f;
      float vv[4];
#pragma unroll
      for (int r = 0; r < 4; ++r) {
        const long row = bm + wr * 64 + mt * 16 + quad * 4 + r;
        const float v = acc[mt][nt][r] + bval;
        vv[r] = v;
        if (outBf16)
          ((unsigned short*)C)[row * ldc + col] = f32_to_bf16(v);
        else
          ((float*)C)[row * ldc + col] = v;
      }
      if (WRITE_VT) {
        if (col >= 2176) {
          const long row0 = bm + wr * 64 + mt * 16 + quad * 4;
          const int b = (int)(row0 >> 11);
          const int s0 = (int)(row0 & 2047);
          const int P = (s0 & ~63) | (((s0 >> 5) & 1) * 32 +
                                      (((s0 >> 2) & 3) * 8) +
                                      (((s0 >> 4) & 1) * 4));
          uint2 w;
          w.x = pack_bf16x2(vv[0], vv[1]);
          w.y = pack_bf16x2(vv[2], vv[3]);
          *(uint2*)&vtout[((long)b * 128 + (col - 2176)) * SEQ + P] = w;
        }
      }
    }
  }
}

// ---------------- gemm_btd: DOUBLE-BUFFERED gemm_bt (attn-style 1-barrier loop) -------
// Per K-tile: sync (drains cur DMA + WAR guard) -> prefetch next tile into buf^1 ->
// compute cur. The vmcnt(0) implicit in __syncthreads now drains loads that have had
// a FULL compute phase in flight, vs gemm_bt's zero-overlap drain. Same proven loop
// shape as mqa_attn. LDS 2x(16+16)=64 KiB -> grid 512 stays 2/CU (no occupancy loss).
// Used for out-proj (<128>, 512 blocks).
template <int BN>
__global__ __launch_bounds__(256) void gemm_btd(
    const unsigned short* __restrict__ A,
    const unsigned short* __restrict__ BT,
    const float* __restrict__ bias,
    void* __restrict__ C, int K, int ldc, int outBf16) {
  constexpr int NT = BN / 32;
  __shared__ unsigned short As[2][128 * 64];
  __shared__ unsigned short Bs[2][BN * 64];
  const int tid = threadIdx.x;
  const int lane = tid & 63;
  const int wave = tid >> 6;
  const int wr = wave >> 1, wc = wave & 1;
  const int ml = lane & 15, quad = lane >> 4;
  const long bm = (long)blockIdx.x * 128;
  const long bn = (long)blockIdx.y * BN;

  const f32x4 zero4 = {0.f, 0.f, 0.f, 0.f};
  f32x4 acc[4][NT];
#pragma unroll
  for (int mt = 0; mt < 4; ++mt)
#pragma unroll
    for (int nt = 0; nt < NT; ++nt) acc[mt][nt] = zero4;

  const int srow = lane >> 3;
  const int scol = ((lane & 7) ^ srow) * 8;

  auto stage = [&](int buf, int k0) {
#pragma unroll
    for (int r = 0; r < 4; ++r) {
      const int rowb = r * 32 + wave * 8;
      gload_lds16(A + (bm + rowb + srow) * (long)K + k0 + scol, &As[buf][rowb * 64]);
    }
#pragma unroll
    for (int r = 0; r < NT; ++r) {
      const int rowb = r * 32 + wave * 8;
      gload_lds16(BT + (bn + rowb + srow) * (long)K + k0 + scol, &Bs[buf][rowb * 64]);
    }
  };

  stage(0, 0);
  const int NTILES = K >> 6;
  for (int t = 0; t < NTILES; ++t) {
    const int cur = t & 1;
    __syncthreads();  // drains cur-tile DMA (in flight for one compute phase); WAR ok
    if (t + 1 < NTILES) stage(cur ^ 1, (t + 1) << 6);
#pragma unroll
    for (int kk = 0; kk < 64; kk += 32) {
      const int g0 = (kk >> 3) + quad;
      bf16x8 af[4], bf[NT];
#pragma unroll
      for (int mt = 0; mt < 4; ++mt)
        af[mt] = *(const bf16x8*)&As[cur][(wr * 64 + mt * 16 + ml) * 64 +
                                          ((g0 ^ (ml & 7)) << 3)];
#pragma unroll
      for (int nt = 0; nt < NT; ++nt)
        bf[nt] = *(const bf16x8*)&Bs[cur][(wc * (BN / 2) + nt * 16 + ml) * 64 +
                                          ((g0 ^ (ml & 7)) << 3)];
#pragma unroll
      for (int mt = 0; mt < 4; ++mt)
#pragma unroll
        for (int nt = 0; nt < NT; ++nt)
          acc[mt][nt] = __builtin_amdgcn_mfma_f32_16x16x32_bf16(
              af[mt], bf[nt], acc[mt][nt], 0, 0, 0);
    }
  }

#pragma unroll
  for (int mt = 0; mt < 4; ++mt) {
#pragma unroll
    for (int nt = 0; nt < NT; ++nt) {
      const long col = bn + wc * (BN / 2) + nt * 16 + ml;
      const float bval = bias ? bias[col] : 0.f;
#pragma unroll
      for (int r = 0; r < 4; ++r) {
        const long row = bm + wr * 64 + mt * 16 + quad * 4 + r;
        const float v = acc[mt][nt][r] + bval;
        if (outBf16)
          ((unsigned short*)C)[row * ldc + col] = f32_to_bf16(v);
        else
          ((float*)C)[row * ldc + col] = v;
      }
    }
  }
}

// ---------------- flash MQA attention (R0/R3 plain-sync body; best measured 73.4) -----
// grid (SEQ/128, NHEADS, NB) = 512 blocks = 2/CU. 32 qrows/wave.
// S^T = K·Q^T (K from LDS dbuf as A, pre-scaled Q registers as B). P = exp2(S) stays
// in registers (v_perm truncation pack) and feeds PV directly as B-operand (V columns
// key-permuted at vt-write). V staged via LDS-DMA dbuf. Row-sums via ones-row MFMA.
// 1 barrier/kt. R4's split counted waits were within-noise-or-worse -> reverted.
__global__ __launch_bounds__(256, 2) void mqa_attn(
    const unsigned short* __restrict__ qkv,  // [B*S][2304]: Q | K(2048) | V(2176)
    const unsigned short* __restrict__ vt,   // [B][128][S], key-permuted per 64
    unsigned short* __restrict__ outp) {     // [B*S][2048]
  __shared__ unsigned short Ks[2][64 * 128];   // 2 x 16 KiB, rows swizzled g^(r&15)
  __shared__ unsigned short VTs[2][128 * 64];  // 2 x 16 KiB, rows swizzled g^(r&7)

  const int lane = threadIdx.x & 63;
  const int wave = threadIdx.x >> 6;
  const int ml = lane & 15, quad = lane >> 4;
  const int h = blockIdx.y, b = blockIdx.z;
  const long q0 = (long)blockIdx.x * 128;
  const long base = (long)b * SEQ;

  // Q fragments (B-operand of S^T); Wq pre-scaled by C2.
  bf16x8 aq[2][4];
#pragma unroll
  for (int n = 0; n < 2; ++n) {
    const unsigned short* qrow =
        qkv + (base + q0 + wave * 32 + n * 16 + ml) * 2304 + h * 128;
#pragma unroll
    for (int ks = 0; ks < 4; ++ks)
      aq[n][ks] = *(const bf16x8*)(qrow + ks * 32 + quad * 8);
  }

  const f32x4 zero4 = {0.f, 0.f, 0.f, 0.f};
  f32x4 o[8][2];
#pragma unroll
  for (int mt2 = 0; mt2 < 8; ++mt2)
#pragma unroll
    for (int n = 0; n < 2; ++n) o[mt2][n] = zero4;
  f32x4 o9[2] = {zero4, zero4};  // ones-row accumulator: row0 = sum_k P = l

  // ones-tile A-frag: row 0 (lane ml==0) = 1.0bf16, other rows 0.
  bf16x8 ones_af;
  {
    union { unsigned u[4]; bf16x8 v; } cv;
    const unsigned w = (ml == 0) ? 0x3F803F80u : 0u;
    cv.u[0] = w; cv.u[1] = w; cv.u[2] = w; cv.u[3] = w;
    ones_af = cv.v;
  }

  // staging lane decomposition
  const int srowK = lane >> 4;
  const int scolK = ((lane & 15) ^ (wave * 4 + srowK)) * 8;
  const int srowV = lane >> 3;
  const int scolV = ((lane & 7) ^ srowV) * 8;
  const unsigned short* kp = qkv + (base + srowK) * 2304 + 2048 + scolK;
  const unsigned short* vp = vt + ((long)b * 128 + srowV) * SEQ + scolV;

  auto stage = [&](int buf, int ktn) {
    const unsigned short* kpp = kp + (long)ktn * (64 * 2304);
    const unsigned short* vpp = vp + ktn * 64;
#pragma unroll
    for (int r = 0; r < 4; ++r) {
      const int rowb = r * 16 + wave * 4;
      gload_lds16(kpp + (long)rowb * 2304, &Ks[buf][rowb * 128]);
    }
#pragma unroll
    for (int r = 0; r < 4; ++r) {
      const int rowb = r * 32 + wave * 8;
      gload_lds16(vpp + (long)rowb * SEQ, &VTs[buf][rowb * 64]);
    }
  };

  stage(0, 0);

  for (int kt = 0; kt < SEQ / 64; ++kt) {
    const int cur = kt & 1;
    __syncthreads();                                // drains cur-buffer DMA
    if (kt < SEQ / 64 - 1) stage(cur ^ 1, kt + 1);  // prefetch overlaps compute

    // S^T = K·Q^T : 4 key-mtiles x 2 qrow-ntiles x 4 ksteps (d); pre-scaled.
    f32x4 s[4][2];
#pragma unroll
    for (int mt = 0; mt < 4; ++mt)
#pragma unroll
      for (int n = 0; n < 2; ++n) s[mt][n] = zero4;
#pragma unroll
    for (int ks = 0; ks < 4; ++ks) {
#pragma unroll
      for (int mt = 0; mt < 4; ++mt) {
        bf16x8 ak = *(const bf16x8*)&Ks[cur][(mt * 16 + ml) * 128 +
                                            (((ks * 4 + quad) ^ ml) << 3)];
#pragma unroll
        for (int n = 0; n < 2; ++n)
          s[mt][n] = __builtin_amdgcn_mfma_f32_16x16x32_bf16(
              ak, aq[n][ks], s[mt][n], 0, 0, 0);
      }
    }

    // P = exp2(S) in registers; truncation-pack to bf16 pairs (1 v_perm each).
    unsigned pk[2][4][2];
#pragma unroll
    for (int mt = 0; mt < 4; ++mt)
#pragma unroll
      for (int n = 0; n < 2; ++n) {
        const float p0 = __builtin_amdgcn_exp2f(s[mt][n][0]);
        const float p1 = __builtin_amdgcn_exp2f(s[mt][n][1]);
        const float p2 = __builtin_amdgcn_exp2f(s[mt][n][2]);
        const float p3 = __builtin_amdgcn_exp2f(s[mt][n][3]);
        pk[n][mt][0] = pack_bf16x2_trunc(p0, p1);
        pk[n][mt][1] = pack_bf16x2_trunc(p2, p3);
      }

    // O^T += V^T·P^T, plus ones-row MFMA accumulating l from the SAME bf16 P.
#pragma unroll
    for (int ks2 = 0; ks2 < 2; ++ks2) {
      bf16x8 bp[2];
#pragma unroll
      for (int n = 0; n < 2; ++n) {
        union { unsigned u[4]; bf16x8 v; } cv;
        cv.u[0] = pk[n][2 * ks2][0];
        cv.u[1] = pk[n][2 * ks2][1];
        cv.u[2] = pk[n][2 * ks2 + 1][0];
        cv.u[3] = pk[n][2 * ks2 + 1][1];
        bp[n] = cv.v;
      }
#pragma unroll
      for (int n = 0; n < 2; ++n)
        o9[n] = __builtin_amdgcn_mfma_f32_16x16x32_bf16(
            ones_af, bp[n], o9[n], 0, 0, 0);
#pragma unroll
      for (int mt2 = 0; mt2 < 8; ++mt2) {
        bf16x8 av = *(const bf16x8*)&VTs[cur][(mt2 * 16 + ml) * 64 +
                                             (((ks2 * 4 + quad) ^ (ml & 7)) << 3)];
#pragma unroll
        for (int n = 0; n < 2; ++n)
          o[mt2][n] = __builtin_amdgcn_mfma_f32_16x16x32_bf16(
              av, bp[n], o[mt2][n], 0, 0, 0);
      }
    }
  }

  // l lives at lane (quad=0, ml) reg0 of o9: broadcast across the 16-group.
  float inv[2];
#pragma unroll
  for (int n = 0; n < 2; ++n)
    inv[n] = 1.f / __shfl(o9[n][0], ml);

  // O^T C-layout: lane holds O[qrow=ml][d = mt2*16+quad*4+r] -> 8B packed stores.
#pragma unroll
  for (int n = 0; n < 2; ++n) {
    const long row = base + q0 + wave * 32 + n * 16 + ml;
#pragma unroll
    for (int mt2 = 0; mt2 < 8; ++mt2) {
      uint2 w;
      w.x = pack_bf16x2(o[mt2][n][0] * inv[n], o[mt2][n][1] * inv[n]);
      w.y = pack_bf16x2(o[mt2][n][2] * inv[n], o[mt2][n][3] * inv[n]);
      *(uint2*)&outp[row * HIDN + h * HDIM + mt2 * 16 + quad * 4] = w;
    }
  }
}

extern "C" void kernel_launch(void* const* d_in, const int* in_sizes, int n_in,
                              void* d_out, int out_size, void* d_ws, size_t ws_size,
                              hipStream_t stream) {
  const float* hidden = (const float*)d_in[0];
  const float* Wq = (const float*)d_in[1];
  const float* bq = (const float*)d_in[2];
  const float* Wk = (const float*)d_in[3];
  const float* bk = (const float*)d_in[4];
  const float* Wv = (const float*)d_in[5];
  const float* bv = (const float*)d_in[6];
  const float* Wo = (const float*)d_in[7];
  const float* bo = (const float*)d_in[8];
  float* out = (float*)d_out;

  char* ws = (char*)d_ws;
  const size_t MB = 1u << 20;
  unsigned short* hb    = (unsigned short*)(ws);            // 16 MiB [4096][2048] bf16 hidden
  unsigned short* attn  = hb;                               // aliases hb (dead after QKV gemm)
  unsigned short* wqkvT = (unsigned short*)(ws + 16 * MB);  // 9 MiB  [2304][2048]
  unsigned short* woT   = (unsigned short*)(ws + 25 * MB);  // 8 MiB  [2048][2048]
  unsigned short* qkv   = (unsigned short*)(ws + 33 * MB);  // 18 MiB [4096][2304]
  unsigned short* vt    = (unsigned short*)(ws + 51 * MB);  // 1 MiB  [2][128][2048]
  float* biasqkv        = (float*)(ws + 52 * MB);           // 9 KiB  [2304]

  // 1. fused prep (cast + all weight transposes + bias concat): 1 launch
  prep<<<16896, 256, 0, stream>>>(hidden, hb, Wq, wqkvT, Wo, woT, Wk, Wv,
                                  wqkvT + (size_t)2048 * 2048,
                                  wqkvT + (size_t)2176 * 2048,
                                  bq, bk, bv, biasqkv);

  // 2. QKV projection (768 blocks = 3/CU exact) + fused key-permuted V transpose
  gemm_bt<96, 1><<<dim3(32, 24), 256, 0, stream>>>(
      hb, wqkvT, biasqkv, qkv, vt, 2048, 2304, 1);

  // 3. attention (512 blocks = 2/CU exact)
  mqa_attn<<<dim3(SEQ / 128, NHEADS, NB), 256, 0, stream>>>(qkv, vt, attn);

  // 4. output projection (512 blocks = 2/CU, attn-style double-buffered loop)
  gemm_btd<128><<<dim3(32, 16), 256, 0, stream>>>(
      attn, woT, bo, out, 2048, 2048, 0);
}